// Round 18
// baseline (158.970 us; speedup 1.0000x reference)
//
#include <hip/hip_runtime.h>
#include <stdint.h>

// Problem constants (from reference): B=8, T=4096, D=1024, H=32.
#define D_DIM 1024
#define T_DIM 4096
#define B_DIM 8
#define M_REAL (B_DIM * (T_DIM + 1))   // 32776 output rows
#define M_MAIN 32768                    // 128 m-panels x 256 (tail 8 rows via GEMV)
#define NWG 512                         // 128 x 4 blocks; 2 blocks/CU resident

typedef short short8 __attribute__((ext_vector_type(8)));   // 8 bf16 (4 VGPRs)
typedef float floatx4 __attribute__((ext_vector_type(4)));  // 4 fp32 acc

typedef const __attribute__((address_space(1))) void* gptr_t;
typedef __attribute__((address_space(3))) void* lptr_t;

__device__ __forceinline__ ushort f2bf(float f) {
  union { float f; uint32_t u; } v; v.f = f;
  uint32_t r = v.u + 0x7FFF + ((v.u >> 16) & 1);  // RNE
  return (ushort)(r >> 16);
}
__device__ __forceinline__ float bf2f(ushort b) {
  union { uint32_t u; float f; } v; v.u = ((uint32_t)b) << 16; return v.f;
}

#define BARRIER()  asm volatile("s_barrier" ::: "memory")
#define WAIT_VM2() asm volatile("s_waitcnt vmcnt(2)" ::: "memory")
#define WAIT_VM0() asm volatile("s_waitcnt vmcnt(0)" ::: "memory")
// rule #18: sched_barrier(0) after the wait so MFMA can't hoist above it.
#define WAIT_LGKM0() do { asm volatile("s_waitcnt lgkmcnt(0)" ::: "memory"); \
                          __builtin_amdgcn_sched_barrier(0); } while (0)
#define SP1() __builtin_amdgcn_s_setprio(1)
#define SP0() __builtin_amdgcn_s_setprio(0)

// ---------------------------------------------------------------------------
// Main GEMM (r12-proven best; DO NOT merge other code paths in — r16 showed
// co-compiled branches perturb regalloc and cost ~16us): C = A @ B^T + bias.
// 256x256 tile, BK=32, 16 waves (4x4, 64x64 per wave), VGPR 64 + acc 64 ->
// 4 waves/SIMD. 2-buffer 64KB LDS -> 2 blocks/CU. Counted prefetch: stage
// tile u+1 at top of iter u into slot (u+1)&1; certify tile u with vmcnt(2);
// vmcnt(0) only at u=31.
// Bank swizzle (0 conflicts): phys chunk = kc ^ ((row>>1)&3) via linear LDS
// dest + pre-swizzled global k ((tid&3)^((tid>>3)&3))*8; read offset
// row*64 + (lhi^((l15>>1)&3))*16. XCD swizzle m204 (nwg=512: q=64, r=0).
// ---------------------------------------------------------------------------
__global__ __launch_bounds__(1024) void gemm_w16_kernel(
    const ushort* __restrict__ A, const ushort* __restrict__ Bm,
    float* __restrict__ C, const float* __restrict__ bias)
{
  __shared__ char smem[65536];   // A slots s*16KB (s=0,1); B at 32768 + s*16KB
  const int tid  = threadIdx.x;
  const int wave = tid >> 6;
  const int lane = tid & 63;
  const int wm = wave >> 2, wn = wave & 3;   // 4x4 wave grid, 64x64 per wave
  const int l15 = lane & 15, lhi = lane >> 4;

  const int bid = blockIdx.x;
  const int wg  = (bid & 7) * 64 + (bid >> 3);
  const int n0 = (wg & 3) * 256;
  const int m0 = (wg >> 2) * 256;            // <= 32512; max row 32767 < M_REAL

  // Staging: thread stages 16B chunk p = tid of the 256x32 tile: row = tid>>2,
  // logical k-chunk = (tid&3) ^ ((tid>>3)&3) (bank swizzle), LDS dest linear.
  const int srow = tid >> 2;                           // 0..255
  const int ksw  = ((tid & 3) ^ ((tid >> 3) & 3)) * 8; // pre-swizzled k elems
  const ushort* Aq = A  + (size_t)(m0 + srow) * D_DIM + ksw;
  const ushort* Bq = Bm + (size_t)(n0 + srow) * D_DIM + ksw;

  // Read-side lane offsets (bytes within a 16KB tile slot).
  const int xorc = (lhi ^ ((l15 >> 1) & 3)) * 16;
  const int aoff = (wm * 64 + l15) * 64 + xorc;
  const int boff = (wn * 64 + l15) * 64 + xorc;

  short8 a[4], b[4];
  floatx4 acc[4][4] = {};

#define STAGE_W(PA, PB, S) do { \
  __builtin_amdgcn_global_load_lds((gptr_t)(PA), \
      (lptr_t)(smem + (S) * 16384 + wave * 1024), 16, 0, 0); \
  __builtin_amdgcn_global_load_lds((gptr_t)(PB), \
      (lptr_t)(smem + 32768 + (S) * 16384 + wave * 1024), 16, 0, 0); \
} while (0)

#define LDAB_W(S) do { \
  _Pragma("unroll") \
  for (int m = 0; m < 4; ++m) \
    a[m] = *(const short8*)(smem + (S) * 16384 + aoff + m * 1024); \
  _Pragma("unroll") \
  for (int n = 0; n < 4; ++n) \
    b[n] = *(const short8*)(smem + 32768 + (S) * 16384 + boff + n * 1024); \
} while (0)

#define MFMA_W() do { \
  _Pragma("unroll") \
  for (int m = 0; m < 4; ++m) \
    _Pragma("unroll") \
    for (int n = 0; n < 4; ++n) \
      acc[m][n] = __builtin_amdgcn_mfma_f32_16x16x32_bf16( \
          a[m], b[n], acc[m][n], 0, 0, 0); \
} while (0)

// One K-tile in slot S0. STG: stage tile u+1 into slot S0^1. VMW: counted wait.
#define ITER_W(S0, STG, VMW) do { \
  if (STG) { STAGE_W(ApS, BpS, (S0) ^ 1); ApS += 32; BpS += 32; } \
  VMW; \
  BARRIER(); \
  LDAB_W(S0); \
  WAIT_LGKM0(); \
  SP1(); MFMA_W(); SP0(); \
  BARRIER(); \
} while (0)

  // Prologue: tile 0 -> slot 0 (2 loads/thread).
  STAGE_W(Aq, Bq, 0);
  const ushort* ApS = Aq + 32;   // next staged tile = 1
  const ushort* BpS = Bq + 32;

#pragma unroll 1
  for (int it = 0; it < 15; ++it) {        // u = 2*it, 2*it+1  (0..29)
    ITER_W(0, 1, WAIT_VM2());
    ITER_W(1, 1, WAIT_VM2());
  }
  ITER_W(0, 1, WAIT_VM2());                // u = 30 (stages tile 31)
  ITER_W(1, 0, WAIT_VM0());                // u = 31

  // Epilogue. C/D layout: col = lane&15, row = (lane>>4)*4 + j.
  // Max gm = 32512 + 192 + 48 + 12 + 3 = 32767 < M_REAL -> no guard.
#pragma unroll
  for (int m = 0; m < 4; ++m)
#pragma unroll
    for (int n = 0; n < 4; ++n) {
      const int gn = n0 + wn * 64 + n * 16 + l15;
      const float bia = bias[gn];
#pragma unroll
      for (int j = 0; j < 4; ++j) {
        const int gm = m0 + wm * 64 + m * 16 + lhi * 4 + j;
        C[(size_t)gm * D_DIM + gn] = acc[m][n][j] + bia;
      }
    }
#undef STAGE_W
#undef LDAB_W
#undef MFMA_W
#undef ITER_W
}

// ---------------------------------------------------------------------------
// Tail GEMV: out[r,c] for r in [32768, 32776), all 1024 cols.
// ---------------------------------------------------------------------------
__global__ __launch_bounds__(256) void tail_gemv_kernel(
    const ushort* __restrict__ S, const ushort* __restrict__ Wf,
    const float* __restrict__ cvec, float* __restrict__ out)
{
  const int wavei = threadIdx.x >> 6, lane = threadIdx.x & 63;
  const int c = blockIdx.x * 4 + wavei;
  float acc[8] = {};
  for (int i = 0; i < 16; ++i) {
    const int k = i * 64 + lane;
    const float wv = bf2f(Wf[(size_t)c * D_DIM + k]);
#pragma unroll
    for (int r = 0; r < 8; ++r)
      acc[r] += wv * bf2f(S[(size_t)(M_MAIN + r) * D_DIM + k]);
  }
#pragma unroll
  for (int r = 0; r < 8; ++r) {
#pragma unroll
    for (int off = 32; off; off >>= 1) acc[r] += __shfl_xor(acc[r], off, 64);
  }
  if (lane == 0) {
    const float bia = cvec[c];
#pragma unroll
    for (int r = 0; r < 8; ++r)
      out[(size_t)(M_MAIN + r) * D_DIM + c] = acc[r] + bia;
  }
}

// ---------------------------------------------------------------------------
// Merged conv + Wfused GEMM (independent work, one launch):
// blocks [0,512): depthwise temporal conv -> S bf16 (CTCH=256 recurrence);
// blocks [512,576): Wfused = Wo @ Wv (m97-style 128x128, BK=64, bf16 out).
// Branch uniform per block; conv path never touches the shared tiles.
// ---------------------------------------------------------------------------
#define CTCH 256
__global__ __launch_bounds__(256) void conv_bt_kernel(
    const float* __restrict__ x, const float* __restrict__ dw,
    ushort* __restrict__ S,
    const ushort* __restrict__ WoB, const ushort* __restrict__ WvT,
    ushort* __restrict__ Wfused)
{
  __shared__ ushort As[128][64];   // 16 KB (gemm_bt path only)
  __shared__ ushort Bs[128][64];   // 16 KB
  const int bid = blockIdx.x;
  const int tid = threadIdx.x;

  if (bid < 512) {
    // ---- Conv: ascending recurrence, batched 32-row window + exact resync.
    // s[t] = (s[t-1] - w0*x[t-33]) / r + w31*x[t-1];  x[neg] = 0.
    const int t0  = (bid & 15) * CTCH;
    const int b   = (bid >> 4) & 7;
    const int col = (bid >> 7) * 256 + tid;

    float w[32];
#pragma unroll
    for (int i = 0; i < 32; ++i) w[i] = dw[i];
    const float rinv = w[0] / w[1];                    // 1/r
    const float w31  = w[31];
    const float c0   = -w[0] * rinv;                   // -(w0/r)

    const float* xb = x + (size_t)b * T_DIM * D_DIM + col;
    ushort*      Sb = S + (size_t)b * (T_DIM + 1) * D_DIM + col;

    float prev[32], cur[32];
    float s;
    if ((bid & 15) == 0) {
#pragma unroll
      for (int i = 0; i < 32; ++i) prev[i] = 0.f;
      s = 0.f;
      Sb[0] = f2bf(0.f);                               // row t=0
    } else {
#pragma unroll
      for (int i = 0; i < 32; ++i) prev[i] = xb[(size_t)(t0 - 32 + i) * D_DIM];
      s = 0.f;
#pragma unroll
      for (int i = 0; i < 32; ++i) s = __builtin_fmaf(w[i], prev[i], s);
    }

#pragma unroll 1
    for (int g = 0; g < 8; g += 2) {
#pragma unroll
      for (int i = 0; i < 32; ++i) cur[i] = xb[(size_t)(t0 + g * 32 + i) * D_DIM];
#pragma unroll
      for (int j = 0; j < 32; ++j) {
        s = __builtin_fmaf(s, rinv, __builtin_fmaf(prev[j], c0, w31 * cur[j]));
        Sb[(size_t)(t0 + g * 32 + 1 + j) * D_DIM] = f2bf(s);
      }
      s = 0.f;                                         // exact resync from cur
#pragma unroll
      for (int i = 0; i < 32; ++i) s = __builtin_fmaf(w[i], cur[i], s);
#pragma unroll
      for (int i = 0; i < 32; ++i) prev[i] = xb[(size_t)(t0 + (g + 1) * 32 + i) * D_DIM];
#pragma unroll
      for (int j = 0; j < 32; ++j) {
        s = __builtin_fmaf(s, rinv, __builtin_fmaf(cur[j], c0, w31 * prev[j]));
        Sb[(size_t)(t0 + (g + 1) * 32 + 1 + j) * D_DIM] = f2bf(s);
      }
      s = 0.f;
#pragma unroll
      for (int i = 0; i < 32; ++i) s = __builtin_fmaf(w[i], prev[i], s);
    }
    return;
  }

  // ---- Wfused = Wo @ Wv  (A = WoB, B^T = WvT, both bf16 row-major K-contig).
  const int bid2 = bid - 512;
  const int wave = tid >> 6;
  const int lane = tid & 63;
  const int wm = wave >> 1, wn = wave & 1;
  const int n0 = (bid2 & 7) * 128, m0 = (bid2 >> 3) * 128;
  const int l15 = lane & 15, lhi = lane >> 4;

  floatx4 acc[4][4] = {};

  const int srow = tid >> 3;
  const int sk8  = (tid & 7) * 8;
  const ushort* Ab = WoB + (size_t)(m0 + srow) * D_DIM + sk8;
  const ushort* Bb = WvT + (size_t)(n0 + srow) * D_DIM + sk8;

  for (int k0 = 0; k0 < D_DIM; k0 += 64) {
#pragma unroll
    for (int q = 0; q < 4; ++q)
      __builtin_amdgcn_global_load_lds((gptr_t)(Ab + k0 + (size_t)q * 32 * D_DIM),
          (lptr_t)((char*)&As[0][0] + (q * 256 + wave * 64) * 16), 16, 0, 0);
#pragma unroll
    for (int q = 0; q < 4; ++q)
      __builtin_amdgcn_global_load_lds((gptr_t)(Bb + k0 + (size_t)q * 32 * D_DIM),
          (lptr_t)((char*)&Bs[0][0] + (q * 256 + wave * 64) * 16), 16, 0, 0);
    __syncthreads();

#pragma unroll
    for (int kk = 0; kk < 2; ++kk) {
      short8 af[4], bfrg[4];
#pragma unroll
      for (int i = 0; i < 4; ++i) {
        af[i]   = *(const short8*)(&As[wm * 64 + i * 16 + l15][kk * 32 + lhi * 8]);
        bfrg[i] = *(const short8*)(&Bs[wn * 64 + i * 16 + l15][kk * 32 + lhi * 8]);
      }
#pragma unroll
      for (int mi = 0; mi < 4; ++mi)
#pragma unroll
        for (int ni = 0; ni < 4; ++ni)
          acc[mi][ni] = __builtin_amdgcn_mfma_f32_16x16x32_bf16(
              af[mi], bfrg[ni], acc[mi][ni], 0, 0, 0);
    }
    __syncthreads();
  }

#pragma unroll
  for (int mi = 0; mi < 4; ++mi)
#pragma unroll
    for (int ni = 0; ni < 4; ++ni) {
      const int gn = n0 + wn * 64 + ni * 16 + l15;
#pragma unroll
      for (int j = 0; j < 4; ++j) {
        const int gm = m0 + wm * 64 + mi * 16 + lhi * 4 + j;
        Wfused[(size_t)gm * D_DIM + gn] = f2bf(acc[mi][ni][j]);
      }
    }
}

// ---------------------------------------------------------------------------
// Merged weight prep: blocks [0,1024): Wo->bf16; [1024,2048): Wv->WvT bf16;
// [2048,2304): cvec[j] = sum(dw)*dot(Wo[j,:],bv) + bo[j].
// ---------------------------------------------------------------------------
__global__ __launch_bounds__(256) void prep_kernel(
    const float* __restrict__ Wo, const float* __restrict__ Wv,
    const float* __restrict__ bv, const float* __restrict__ bo,
    const float* __restrict__ dw,
    ushort* __restrict__ WoB, ushort* __restrict__ WvT,
    float* __restrict__ cvec)
{
  __shared__ float tile[32][33];
  const int bid = blockIdx.x;
  const int tid = threadIdx.x;

  if (bid < 1024) {            // Wo fp32 -> bf16 straight copy (float4)
    const int i = bid * 256 + tid;
    const float4 v = ((const float4*)Wo)[i];
    ushort4 o = make_ushort4(f2bf(v.x), f2bf(v.y), f2bf(v.z), f2bf(v.w));
    *(ushort4*)(WoB + (size_t)i * 4) = o;
  } else if (bid < 2048) {     // Wv transpose -> WvT bf16 (32x32 LDS tile)
    const int b2 = bid - 1024;
    const int c0 = (b2 & 31) * 32, r0 = (b2 >> 5) * 32;
    const int tx = tid & 31, ty = tid >> 5;    // 32 x 8
#pragma unroll
    for (int j = 0; j < 4; ++j)
      tile[ty + j * 8][tx] = Wv[(size_t)(r0 + ty + j * 8) * D_DIM + c0 + tx];
    __syncthreads();
#pragma unroll
    for (int j = 0; j < 4; ++j)
      WvT[(size_t)(c0 + ty + j * 8) * D_DIM + r0 + tx] = f2bf(tile[tx][ty + j * 8]);
  } else {                     // bias vector, one wave per j
    const int j    = (bid - 2048) * 4 + (tid >> 6);
    const int lane = tid & 63;
    float sumw = 0.f;
#pragma unroll
    for (int i = 0; i < 32; ++i) sumw += dw[i];
    float s = 0.f;
    for (int k = lane; k < D_DIM; k += 64) s += Wo[(size_t)j * D_DIM + k] * bv[k];
#pragma unroll
    for (int off = 32; off; off >>= 1) s += __shfl_xor(s, off, 64);
    if (lane == 0) cvec[j] = sumw * s + bo[j];
  }
}

// ---------------------------------------------------------------------------
extern "C" void kernel_launch(void* const* d_in, const int* in_sizes, int n_in,
                              void* d_out, int out_size, void* d_ws, size_t ws_size,
                              hipStream_t stream) {
  const float* x  = (const float*)d_in[0];
  const float* Wv = (const float*)d_in[1];
  const float* bv = (const float*)d_in[2];
  const float* Wo = (const float*)d_in[3];
  const float* bo = (const float*)d_in[4];
  const float* dw = (const float*)d_in[5];
  float* out = (float*)d_out;

  // Workspace layout (~73.4 MB total).
  char* ws = (char*)d_ws;
  ushort* S      = (ushort*)ws;                                  // M_REAL*1024 bf16
  ushort* WoB    = (ushort*)(ws + (size_t)M_REAL * D_DIM * 2);   // 1024^2 bf16
  ushort* WvT    = WoB + (size_t)D_DIM * D_DIM;                  // 1024^2 bf16
  ushort* Wfused = WvT + (size_t)D_DIM * D_DIM;                  // 1024^2 bf16
  float*  cvec   = (float*)(Wfused + (size_t)D_DIM * D_DIM);     // 1024 fp32

  // 1) Merged weight prep.
  prep_kernel<<<dim3(2304), dim3(256), 0, stream>>>(
      Wo, Wv, bv, bo, dw, WoB, WvT, cvec);

  // 2) conv (512 blocks) || Wfused GEMM (64 blocks) — one launch.
  conv_bt_kernel<<<dim3(576), dim3(256), 0, stream>>>(
      x, dw, S, WoB, WvT, Wfused);

  // 3) out = s @ Wfused^T + cvec  (r12 gemm, pristine codegen).
  gemm_w16_kernel<<<dim3(NWG), dim3(1024), 0, stream>>>(S, Wfused, out, cvec);

  // 4) 8-row tail GEMV (tiny).
  tail_gemv_kernel<<<dim3(256), dim3(256), 0, stream>>>(S, Wfused, cvec, out);
}

// Round 19
// 157.849 us; speedup vs baseline: 1.0071x; 1.0071x over previous
//
#include <hip/hip_runtime.h>
#include <stdint.h>

// Problem constants (from reference): B=8, T=4096, D=1024, H=32.
#define D_DIM 1024
#define T_DIM 4096
#define B_DIM 8
#define M_REAL (B_DIM * (T_DIM + 1))   // 32776 output rows
#define M_MAIN 32768                    // 128 m-panels x 256 (tail 8 rows via GEMV)
#define NWG 1024                        // 128 m-panels x 8 n-panels

typedef short short8 __attribute__((ext_vector_type(8)));   // 8 bf16 (4 VGPRs)
typedef float floatx4 __attribute__((ext_vector_type(4)));  // 4 fp32 acc

typedef const __attribute__((address_space(1))) void* gptr_t;
typedef __attribute__((address_space(3))) void* lptr_t;

__device__ __forceinline__ ushort f2bf(float f) {
  union { float f; uint32_t u; } v; v.f = f;
  uint32_t r = v.u + 0x7FFF + ((v.u >> 16) & 1);  // RNE
  return (ushort)(r >> 16);
}
__device__ __forceinline__ float bf2f(ushort b) {
  union { uint32_t u; float f; } v; v.u = ((uint32_t)b) << 16; return v.f;
}

#define BARRIER()  asm volatile("s_barrier" ::: "memory")
#define WAIT_VM3() asm volatile("s_waitcnt vmcnt(3)" ::: "memory")
#define WAIT_VM0() asm volatile("s_waitcnt vmcnt(0)" ::: "memory")
// rule #18: sched_barrier(0) after the wait so MFMA can't hoist above it.
#define WAIT_LGKM0() do { asm volatile("s_waitcnt lgkmcnt(0)" ::: "memory"); \
                          __builtin_amdgcn_sched_barrier(0); } while (0)
#define SP1() __builtin_amdgcn_s_setprio(1)
#define SP0() __builtin_amdgcn_s_setprio(0)

// ---------------------------------------------------------------------------
// Main GEMM: C[m,n] = sum_k A[m,k]*B[n,k] + bias[n].  A,B bf16 row-major.
// r12 template reshaped 256x256/16w -> **256x128 tile, 8 waves (4m x 2n)**:
// r18's insight — r12's 16 waves x 128 regs filled the whole register file,
// so only ONE barrier-locked block was resident and the LDS port idled
// during MFMA phases. 8-wave blocks (2 waves/SIMD x 128 regs = 256) let TWO
// INDEPENDENT blocks co-reside per CU, naturally phase-skewed -> one block's
// ds_reads overlap the other's MFMA (m114 mechanism across blocks).
// 2-buffer 48KB LDS (A 2x16KB at 0, B 2x8KB at +32768). Counted prefetch:
// per iter stage tile u+1 (3 gload_lds/thread: A row srow, A row srow+128,
// B row srow) into slot (u&1)^1; certify tile u with vmcnt(3); vmcnt(0) only
// at u=31. Slot overwrite is first-op after the trailing barrier whose reads
// completed the previous occupant -> race-free (r12 discipline).
// Bank swizzle (r12-proven, 0 conflicts): linear LDS dest + pre-swizzled
// global k ((tid&3)^((tid>>3)&3))*8; read offset row*64 + (lhi^((l15>>1)&3))*16.
// XCD swizzle (bijective, nwg=1024): wg=(bid&7)*128+(bid>>3), n fastest ->
// each XCD owns 16 disjoint m-panels (A fetched once from HBM, L2-resident
// per k-step; B 2MB resident on every XCD).
// ---------------------------------------------------------------------------
__global__ __launch_bounds__(512, 4) void gemm_w8_kernel(
    const ushort* __restrict__ A, const ushort* __restrict__ Bm,
    float* __restrict__ C, const float* __restrict__ bias)
{
  __shared__ char smem[49152];   // A slots s*16KB; B slots 32768 + s*8KB
  const int tid  = threadIdx.x;
  const int wave = tid >> 6;
  const int lane = tid & 63;
  const int wm = wave >> 1, wn = wave & 1;   // 4m x 2n wave grid, 64x64/wave
  const int l15 = lane & 15, lhi = lane >> 4;

  const int bid = blockIdx.x;
  const int wg  = (bid & 7) * 128 + (bid >> 3);
  const int n0 = (wg & 7) * 128;
  const int m0 = (wg >> 3) * 256;            // <= 32512; max row 32767 < M_REAL

  // Staging: thread stages 16B chunks {tid, 512+tid} of A (rows srow,
  // srow+128) and chunk tid of B (row srow); row = tid>>2, pre-swizzled k.
  const int srow = tid >> 2;                           // 0..127
  const int ksw  = ((tid & 3) ^ ((tid >> 3) & 3)) * 8; // pre-swizzled k elems
  const ushort* Aq0 = A  + (size_t)(m0 + srow) * D_DIM + ksw;
  const ushort* Aq1 = A  + (size_t)(m0 + 128 + srow) * D_DIM + ksw;
  const ushort* Bq  = Bm + (size_t)(n0 + srow) * D_DIM + ksw;

  // Read-side lane offsets (bytes within a tile slot).
  const int xorc = (lhi ^ ((l15 >> 1) & 3)) * 16;
  const int aoff = (wm * 64 + l15) * 64 + xorc;        // within 16KB A slot
  const int boff = (wn * 64 + l15) * 64 + xorc;        // within 8KB  B slot

  short8 a[4], b[4];
  floatx4 acc[4][4] = {};

#define STAGE_W(S) do { \
  __builtin_amdgcn_global_load_lds((gptr_t)(Aq0 + koff), \
      (lptr_t)(smem + (S) * 16384 + wave * 1024), 16, 0, 0); \
  __builtin_amdgcn_global_load_lds((gptr_t)(Aq1 + koff), \
      (lptr_t)(smem + (S) * 16384 + 8192 + wave * 1024), 16, 0, 0); \
  __builtin_amdgcn_global_load_lds((gptr_t)(Bq + koff), \
      (lptr_t)(smem + 32768 + (S) * 8192 + wave * 1024), 16, 0, 0); \
  koff += 32; \
} while (0)

#define LDAB_W(S) do { \
  _Pragma("unroll") \
  for (int m = 0; m < 4; ++m) \
    a[m] = *(const short8*)(smem + (S) * 16384 + aoff + m * 1024); \
  _Pragma("unroll") \
  for (int n = 0; n < 4; ++n) \
    b[n] = *(const short8*)(smem + 32768 + (S) * 8192 + boff + n * 1024); \
} while (0)

#define MFMA_W() do { \
  _Pragma("unroll") \
  for (int m = 0; m < 4; ++m) \
    _Pragma("unroll") \
    for (int n = 0; n < 4; ++n) \
      acc[m][n] = __builtin_amdgcn_mfma_f32_16x16x32_bf16( \
          a[m], b[n], acc[m][n], 0, 0, 0); \
} while (0)

// One K-tile in slot S0. STG: stage tile u+1 into slot S0^1. VMW: counted wait.
#define ITER_W(S0, STG, VMW) do { \
  if (STG) STAGE_W((S0) ^ 1); \
  VMW; \
  BARRIER(); \
  LDAB_W(S0); \
  WAIT_LGKM0(); \
  SP1(); MFMA_W(); SP0(); \
  BARRIER(); \
} while (0)

  // Prologue: tile 0 -> slot 0 (3 loads/thread).
  int koff = 0;
  STAGE_W(0);

#pragma unroll 1
  for (int it = 0; it < 15; ++it) {        // u = 2*it, 2*it+1  (0..29)
    ITER_W(0, 1, WAIT_VM3());
    ITER_W(1, 1, WAIT_VM3());
  }
  ITER_W(0, 1, WAIT_VM3());                // u = 30 (stages tile 31)
  ITER_W(1, 0, WAIT_VM0());                // u = 31

  // Epilogue. C/D layout: col = lane&15, row = (lane>>4)*4 + j.
  // Max gm = 32512 + 192 + 48 + 12 + 3 = 32767 < M_REAL -> no guard.
#pragma unroll
  for (int m = 0; m < 4; ++m)
#pragma unroll
    for (int n = 0; n < 4; ++n) {
      const int gn = n0 + wn * 64 + n * 16 + l15;
      const float bia = bias[gn];
#pragma unroll
      for (int j = 0; j < 4; ++j) {
        const int gm = m0 + wm * 64 + m * 16 + lhi * 4 + j;
        C[(size_t)gm * D_DIM + gn] = acc[m][n][j] + bia;
      }
    }
#undef STAGE_W
#undef LDAB_W
#undef MFMA_W
#undef ITER_W
}

// ---------------------------------------------------------------------------
// Tail GEMV: out[r,c] for r in [32768, 32776), all 1024 cols.
// ---------------------------------------------------------------------------
__global__ __launch_bounds__(256) void tail_gemv_kernel(
    const ushort* __restrict__ S, const ushort* __restrict__ Wf,
    const float* __restrict__ cvec, float* __restrict__ out)
{
  const int wavei = threadIdx.x >> 6, lane = threadIdx.x & 63;
  const int c = blockIdx.x * 4 + wavei;
  float acc[8] = {};
  for (int i = 0; i < 16; ++i) {
    const int k = i * 64 + lane;
    const float wv = bf2f(Wf[(size_t)c * D_DIM + k]);
#pragma unroll
    for (int r = 0; r < 8; ++r)
      acc[r] += wv * bf2f(S[(size_t)(M_MAIN + r) * D_DIM + k]);
  }
#pragma unroll
  for (int r = 0; r < 8; ++r) {
#pragma unroll
    for (int off = 32; off; off >>= 1) acc[r] += __shfl_xor(acc[r], off, 64);
  }
  if (lane == 0) {
    const float bia = cvec[c];
#pragma unroll
    for (int r = 0; r < 8; ++r)
      out[(size_t)(M_MAIN + r) * D_DIM + c] = acc[r] + bia;
  }
}

// ---------------------------------------------------------------------------
// Small GEMM for Wfused = Wo @ Wv (bf16 out): m97-style 128x128 tile, BK=64.
// ---------------------------------------------------------------------------
__global__ __launch_bounds__(256) void gemm_bt_kernel(
    const ushort* __restrict__ A, const ushort* __restrict__ Bm,
    ushort* __restrict__ Cb, int K, int N)
{
  __shared__ ushort As[128][64];   // 16 KB
  __shared__ ushort Bs[128][64];   // 16 KB
  const int tid  = threadIdx.x;
  const int wave = tid >> 6;
  const int lane = tid & 63;
  const int wm = wave >> 1, wn = wave & 1;
  const int n0 = blockIdx.x * 128, m0 = blockIdx.y * 128;
  const int l15 = lane & 15, lhi = lane >> 4;

  floatx4 acc[4][4] = {};

  const int srow = tid >> 3;
  const int sk8  = (tid & 7) * 8;
  const ushort* Ab = A  + (size_t)(m0 + srow) * K + sk8;
  const ushort* Bb = Bm + (size_t)(n0 + srow) * K + sk8;

  for (int k0 = 0; k0 < K; k0 += 64) {
#pragma unroll
    for (int q = 0; q < 4; ++q)
      __builtin_amdgcn_global_load_lds((gptr_t)(Ab + k0 + (size_t)q * 32 * K),
          (lptr_t)((char*)&As[0][0] + (q * 256 + wave * 64) * 16), 16, 0, 0);
#pragma unroll
    for (int q = 0; q < 4; ++q)
      __builtin_amdgcn_global_load_lds((gptr_t)(Bb + k0 + (size_t)q * 32 * K),
          (lptr_t)((char*)&Bs[0][0] + (q * 256 + wave * 64) * 16), 16, 0, 0);
    __syncthreads();

#pragma unroll
    for (int kk = 0; kk < 2; ++kk) {
      short8 af[4], bfrg[4];
#pragma unroll
      for (int i = 0; i < 4; ++i) {
        af[i]   = *(const short8*)(&As[wm * 64 + i * 16 + l15][kk * 32 + lhi * 8]);
        bfrg[i] = *(const short8*)(&Bs[wn * 64 + i * 16 + l15][kk * 32 + lhi * 8]);
      }
#pragma unroll
      for (int mi = 0; mi < 4; ++mi)
#pragma unroll
        for (int ni = 0; ni < 4; ++ni)
          acc[mi][ni] = __builtin_amdgcn_mfma_f32_16x16x32_bf16(
              af[mi], bfrg[ni], acc[mi][ni], 0, 0, 0);
    }
    __syncthreads();
  }

#pragma unroll
  for (int mi = 0; mi < 4; ++mi)
#pragma unroll
    for (int ni = 0; ni < 4; ++ni) {
      const int gn = n0 + wn * 64 + ni * 16 + l15;
#pragma unroll
      for (int j = 0; j < 4; ++j) {
        const int gm = m0 + wm * 64 + mi * 16 + lhi * 4 + j;
        Cb[(size_t)gm * N + gn] = f2bf(acc[mi][ni][j]);
      }
    }
}

// ---------------------------------------------------------------------------
// Depthwise temporal conv -> s_bf16 (standalone; r15-proven).
// s[t] = sum_i w[i] x[t-32+i] (x[neg]=0), t in [0,4096].
// Ascending recurrence with batched 32-row register window + exact resync:
//   s[t] = (s[t-1] - w0*x[t-33]) / r + w31*x[t-1]
// CTCH=256: reads 1.125 rows/output. Grid (16, 8, 4) = 512 blocks.
// ---------------------------------------------------------------------------
#define CTCH 256
__global__ __launch_bounds__(256) void conv_kernel(
    const float* __restrict__ x, const float* __restrict__ dw,
    ushort* __restrict__ S)
{
  const int b   = blockIdx.y;
  const int col = blockIdx.z * 256 + threadIdx.x;   // 0..1023
  const int t0  = blockIdx.x * CTCH;

  float w[32];
#pragma unroll
  for (int i = 0; i < 32; ++i) w[i] = dw[i];
  const float rinv = w[0] / w[1];                    // 1/r
  const float w31  = w[31];
  const float c0   = -w[0] * rinv;                   // -(w0/r)

  const float* xb = x + (size_t)b * T_DIM * D_DIM + col;
  ushort*      Sb = S + (size_t)b * (T_DIM + 1) * D_DIM + col;

  float prev[32], cur[32];
  float s;
  if (blockIdx.x == 0) {
#pragma unroll
    for (int i = 0; i < 32; ++i) prev[i] = 0.f;
    s = 0.f;
    Sb[0] = f2bf(0.f);                               // row t=0
  } else {
#pragma unroll
    for (int i = 0; i < 32; ++i) prev[i] = xb[(size_t)(t0 - 32 + i) * D_DIM];
    s = 0.f;
#pragma unroll
    for (int i = 0; i < 32; ++i) s = __builtin_fmaf(w[i], prev[i], s);
  }

#pragma unroll 1
  for (int g = 0; g < 8; g += 2) {
#pragma unroll
    for (int i = 0; i < 32; ++i) cur[i] = xb[(size_t)(t0 + g * 32 + i) * D_DIM];
#pragma unroll
    for (int j = 0; j < 32; ++j) {
      s = __builtin_fmaf(s, rinv, __builtin_fmaf(prev[j], c0, w31 * cur[j]));
      Sb[(size_t)(t0 + g * 32 + 1 + j) * D_DIM] = f2bf(s);
    }
    s = 0.f;                                         // exact resync from cur
#pragma unroll
    for (int i = 0; i < 32; ++i) s = __builtin_fmaf(w[i], cur[i], s);
#pragma unroll
    for (int i = 0; i < 32; ++i) prev[i] = xb[(size_t)(t0 + (g + 1) * 32 + i) * D_DIM];
#pragma unroll
    for (int j = 0; j < 32; ++j) {
      s = __builtin_fmaf(s, rinv, __builtin_fmaf(cur[j], c0, w31 * prev[j]));
      Sb[(size_t)(t0 + (g + 1) * 32 + 1 + j) * D_DIM] = f2bf(s);
    }
    s = 0.f;
#pragma unroll
    for (int i = 0; i < 32; ++i) s = __builtin_fmaf(w[i], prev[i], s);
  }
}

// ---------------------------------------------------------------------------
// Merged weight prep: blocks [0,1024): Wo->bf16; [1024,2048): Wv->WvT bf16;
// [2048,2304): cvec[j] = sum(dw)*dot(Wo[j,:],bv) + bo[j].
// ---------------------------------------------------------------------------
__global__ __launch_bounds__(256) void prep_kernel(
    const float* __restrict__ Wo, const float* __restrict__ Wv,
    const float* __restrict__ bv, const float* __restrict__ bo,
    const float* __restrict__ dw,
    ushort* __restrict__ WoB, ushort* __restrict__ WvT,
    float* __restrict__ cvec)
{
  __shared__ float tile[32][33];
  const int bid = blockIdx.x;
  const int tid = threadIdx.x;

  if (bid < 1024) {            // Wo fp32 -> bf16 straight copy (float4)
    const int i = bid * 256 + tid;
    const float4 v = ((const float4*)Wo)[i];
    ushort4 o = make_ushort4(f2bf(v.x), f2bf(v.y), f2bf(v.z), f2bf(v.w));
    *(ushort4*)(WoB + (size_t)i * 4) = o;
  } else if (bid < 2048) {     // Wv transpose -> WvT bf16 (32x32 LDS tile)
    const int b2 = bid - 1024;
    const int c0 = (b2 & 31) * 32, r0 = (b2 >> 5) * 32;
    const int tx = tid & 31, ty = tid >> 5;    // 32 x 8
#pragma unroll
    for (int j = 0; j < 4; ++j)
      tile[ty + j * 8][tx] = Wv[(size_t)(r0 + ty + j * 8) * D_DIM + c0 + tx];
    __syncthreads();
#pragma unroll
    for (int j = 0; j < 4; ++j)
      WvT[(size_t)(c0 + ty + j * 8) * D_DIM + r0 + tx] = f2bf(tile[tx][ty + j * 8]);
  } else {                     // bias vector, one wave per j
    const int j    = (bid - 2048) * 4 + (tid >> 6);
    const int lane = tid & 63;
    float sumw = 0.f;
#pragma unroll
    for (int i = 0; i < 32; ++i) sumw += dw[i];
    float s = 0.f;
    for (int k = lane; k < D_DIM; k += 64) s += Wo[(size_t)j * D_DIM + k] * bv[k];
#pragma unroll
    for (int off = 32; off; off >>= 1) s += __shfl_xor(s, off, 64);
    if (lane == 0) cvec[j] = sumw * s + bo[j];
  }
}

// ---------------------------------------------------------------------------
extern "C" void kernel_launch(void* const* d_in, const int* in_sizes, int n_in,
                              void* d_out, int out_size, void* d_ws, size_t ws_size,
                              hipStream_t stream) {
  const float* x  = (const float*)d_in[0];
  const float* Wv = (const float*)d_in[1];
  const float* bv = (const float*)d_in[2];
  const float* Wo = (const float*)d_in[3];
  const float* bo = (const float*)d_in[4];
  const float* dw = (const float*)d_in[5];
  float* out = (float*)d_out;

  // Workspace layout (~73.4 MB total).
  char* ws = (char*)d_ws;
  ushort* S      = (ushort*)ws;                                  // M_REAL*1024 bf16
  ushort* WoB    = (ushort*)(ws + (size_t)M_REAL * D_DIM * 2);   // 1024^2 bf16
  ushort* WvT    = WoB + (size_t)D_DIM * D_DIM;                  // 1024^2 bf16
  ushort* Wfused = WvT + (size_t)D_DIM * D_DIM;                  // 1024^2 bf16
  float*  cvec   = (float*)(Wfused + (size_t)D_DIM * D_DIM);     // 1024 fp32

  // 1) Merged weight prep.
  prep_kernel<<<dim3(2304), dim3(256), 0, stream>>>(
      Wo, Wv, bv, bo, dw, WoB, WvT, cvec);

  // 2) Wfused = Wo @ Wv  (standalone, pristine codegen).
  gemm_bt_kernel<<<dim3(8, 8), dim3(256), 0, stream>>>(
      WoB, WvT, Wfused, D_DIM, D_DIM);

  // 3) Temporal conv -> s bf16 (standalone, pristine codegen).
  conv_kernel<<<dim3(T_DIM / CTCH, B_DIM, 4), dim3(256), 0, stream>>>(x, dw, S);

  // 4) out = s @ Wfused^T + cvec  (256x128, 8 waves, 2 independent
  //    blocks/CU, counted vmcnt(3), XCD-swizzled).
  gemm_w8_kernel<<<dim3(NWG), dim3(512), 0, stream>>>(S, Wfused, out, cvec);

  // 5) 8-row tail GEMV (tiny).
  tail_gemv_kernel<<<dim3(256), dim3(256), 0, stream>>>(S, Wfused, cvec, out);
}

// Round 20
// 153.998 us; speedup vs baseline: 1.0323x; 1.0250x over previous
//
#include <hip/hip_runtime.h>
#include <stdint.h>

// Problem constants (from reference): B=8, T=4096, D=1024, H=32.
#define D_DIM 1024
#define T_DIM 4096
#define B_DIM 8
#define M_REAL (B_DIM * (T_DIM + 1))   // 32776 output rows
#define M_MAIN 32768                    // 128 m-panels x 256 (tail 8 rows via GEMV)
#define NWG 512                         // 128 x 4 blocks; 1 block/CU, 2 rounds

typedef short short8 __attribute__((ext_vector_type(8)));   // 8 bf16 (4 VGPRs)
typedef float floatx4 __attribute__((ext_vector_type(4)));  // 4 fp32 acc

typedef const __attribute__((address_space(1))) void* gptr_t;
typedef __attribute__((address_space(3))) void* lptr_t;

__device__ __forceinline__ ushort f2bf(float f) {
  union { float f; uint32_t u; } v; v.f = f;
  uint32_t r = v.u + 0x7FFF + ((v.u >> 16) & 1);  // RNE
  return (ushort)(r >> 16);
}
__device__ __forceinline__ float bf2f(ushort b) {
  union { uint32_t u; float f; } v; v.u = ((uint32_t)b) << 16; return v.f;
}

#define BARRIER()  asm volatile("s_barrier" ::: "memory")
#define WAIT_VM2() asm volatile("s_waitcnt vmcnt(2)" ::: "memory")
#define WAIT_VM0() asm volatile("s_waitcnt vmcnt(0)" ::: "memory")
// rule #18: sched_barrier(0) after the wait so MFMA can't hoist above it.
#define WAIT_LGKM0() do { asm volatile("s_waitcnt lgkmcnt(0)" ::: "memory"); \
                          __builtin_amdgcn_sched_barrier(0); } while (0)
#define SP1() __builtin_amdgcn_s_setprio(1)
#define SP0() __builtin_amdgcn_s_setprio(0)

// ---------------------------------------------------------------------------
// Main GEMM: C[m,n] = sum_k A[m,k]*B[n,k] + bias[n].  A,B bf16 row-major.
// 256x256 tile, BK=32, 16 waves (4x4, 64x64/wave), 3-buffer 96KB LDS,
// **ONE barrier per K-tile** (r11's 2-barrier 3-buf ran 86us; trailing
// barrier proven redundant once stage moves AFTER the leading barrier):
//   iter u: vmcnt(2) -> BARRIER -> stage tile u+2 -> slot (u+2)%3
//           -> ds_read slot u%3 -> lgkm(0) -> MFMA.
// Race audit:
//  * certify: at iter u top, outstanding vmem = tile u+1's 2 loads (stage of
//    iter u-1) -> vmcnt(2) guarantees tile u (staged iter u-2) landed.
//  * slot overwrite: stage(iter u) writes slot (u+2)%3 = (u-1)%3, last READ
//    at iter u-1. Every wave does lgkm(0) before its MFMA, so its iter u-1
//    reads are complete before it reaches barrier u; stage is after barrier u
//    -> no read-overwrite race.
//  * read-vs-write: LDAB(slot u%3) reads data certified by this iter's
//    vmcnt; the next write to that slot is stage(iter u+1), which sits after
//    barrier u+1 — a slow wave still reading holds everyone at barrier u+1.
//  * WAW on slot: previous write landed by iter u's vmcnt. All safe.
// Bank swizzle (0 conflicts, r12-proven): linear LDS dest + pre-swizzled
// global k ((tid&3)^((tid>>3)&3))*8; read offset row*64+(lhi^((l15>>1)&3))*16.
// XCD swizzle m204 (nwg=512: q=64, r=0).
// ---------------------------------------------------------------------------
__global__ __launch_bounds__(1024) void gemm_w16_kernel(
    const ushort* __restrict__ A, const ushort* __restrict__ Bm,
    float* __restrict__ C, const float* __restrict__ bias)
{
  __shared__ char smem[98304];   // A slots s*16KB (s=0..2); B at 49152 + s*16KB
  const int tid  = threadIdx.x;
  const int wave = tid >> 6;
  const int lane = tid & 63;
  const int wm = wave >> 2, wn = wave & 3;   // 4x4 wave grid, 64x64 per wave
  const int l15 = lane & 15, lhi = lane >> 4;

  const int bid = blockIdx.x;
  const int wg  = (bid & 7) * 64 + (bid >> 3);
  const int n0 = (wg & 3) * 256;
  const int m0 = (wg >> 2) * 256;            // <= 32512; max row 32767 < M_REAL

  // Staging: thread stages 16B chunk p = tid of the 256x32 tile: row = tid>>2,
  // logical k-chunk = (tid&3) ^ ((tid>>3)&3) (bank swizzle), LDS dest linear.
  const int srow = tid >> 2;                           // 0..255
  const int ksw  = ((tid & 3) ^ ((tid >> 3) & 3)) * 8; // pre-swizzled k elems
  const ushort* Aq = A  + (size_t)(m0 + srow) * D_DIM + ksw;
  const ushort* Bq = Bm + (size_t)(n0 + srow) * D_DIM + ksw;

  // Read-side lane offsets (bytes within a 16KB tile slot).
  const int xorc = (lhi ^ ((l15 >> 1) & 3)) * 16;
  const int aoff = (wm * 64 + l15) * 64 + xorc;
  const int boff = (wn * 64 + l15) * 64 + xorc;

  short8 a[4], b[4];
  floatx4 acc[4][4] = {};

#define STAGE_W(S) do { \
  __builtin_amdgcn_global_load_lds((gptr_t)(Aq + koff), \
      (lptr_t)(smem + (S) * 16384 + wave * 1024), 16, 0, 0); \
  __builtin_amdgcn_global_load_lds((gptr_t)(Bq + koff), \
      (lptr_t)(smem + 49152 + (S) * 16384 + wave * 1024), 16, 0, 0); \
  koff += 32; \
} while (0)

#define LDAB_W(S) do { \
  _Pragma("unroll") \
  for (int m = 0; m < 4; ++m) \
    a[m] = *(const short8*)(smem + (S) * 16384 + aoff + m * 1024); \
  _Pragma("unroll") \
  for (int n = 0; n < 4; ++n) \
    b[n] = *(const short8*)(smem + 49152 + (S) * 16384 + boff + n * 1024); \
} while (0)

#define MFMA_W() do { \
  _Pragma("unroll") \
  for (int m = 0; m < 4; ++m) \
    _Pragma("unroll") \
    for (int n = 0; n < 4; ++n) \
      acc[m][n] = __builtin_amdgcn_mfma_f32_16x16x32_bf16( \
          a[m], b[n], acc[m][n], 0, 0, 0); \
} while (0)

// One K-tile: consume slot S0; stage (if STG) the tile 2 ahead into slot S2.
// ONE barrier per tile; stage sits after the barrier (see race audit above).
#define ITER_W(S0, S2, STG, VMW) do { \
  VMW; \
  BARRIER(); \
  if (STG) STAGE_W(S2); \
  LDAB_W(S0); \
  WAIT_LGKM0(); \
  SP1(); MFMA_W(); SP0(); \
} while (0)

  // Prologue: tile 0 -> slot 0, tile 1 -> slot 1 (4 loads/thread).
  int koff = 0;
  STAGE_W(0);
  STAGE_W(1);

#pragma unroll 1
  for (int it = 0; it < 10; ++it) {        // u = 3*it .. 3*it+2  (0..29)
    ITER_W(0, 2, 1, WAIT_VM2());
    ITER_W(1, 0, 1, WAIT_VM2());
    ITER_W(2, 1, 1, WAIT_VM2());
  }
  ITER_W(0, 2, 0, WAIT_VM2());             // u = 30 (tile 31 still in flight)
  ITER_W(1, 0, 0, WAIT_VM0());             // u = 31

  // Epilogue. C/D layout: col = lane&15, row = (lane>>4)*4 + j.
  // Max gm = 32512 + 192 + 48 + 12 + 3 = 32767 < M_REAL -> no guard.
#pragma unroll
  for (int m = 0; m < 4; ++m)
#pragma unroll
    for (int n = 0; n < 4; ++n) {
      const int gn = n0 + wn * 64 + n * 16 + l15;
      const float bia = bias[gn];
#pragma unroll
      for (int j = 0; j < 4; ++j) {
        const int gm = m0 + wm * 64 + m * 16 + lhi * 4 + j;
        C[(size_t)gm * D_DIM + gn] = acc[m][n][j] + bia;
      }
    }
#undef STAGE_W
#undef LDAB_W
#undef MFMA_W
#undef ITER_W
}

// ---------------------------------------------------------------------------
// Tail GEMV: out[r,c] for r in [32768, 32776), all 1024 cols.
// ---------------------------------------------------------------------------
__global__ __launch_bounds__(256) void tail_gemv_kernel(
    const ushort* __restrict__ S, const ushort* __restrict__ Wf,
    const float* __restrict__ cvec, float* __restrict__ out)
{
  const int wavei = threadIdx.x >> 6, lane = threadIdx.x & 63;
  const int c = blockIdx.x * 4 + wavei;
  float acc[8] = {};
  for (int i = 0; i < 16; ++i) {
    const int k = i * 64 + lane;
    const float wv = bf2f(Wf[(size_t)c * D_DIM + k]);
#pragma unroll
    for (int r = 0; r < 8; ++r)
      acc[r] += wv * bf2f(S[(size_t)(M_MAIN + r) * D_DIM + k]);
  }
#pragma unroll
  for (int r = 0; r < 8; ++r) {
#pragma unroll
    for (int off = 32; off; off >>= 1) acc[r] += __shfl_xor(acc[r], off, 64);
  }
  if (lane == 0) {
    const float bia = cvec[c];
#pragma unroll
    for (int r = 0; r < 8; ++r)
      out[(size_t)(M_MAIN + r) * D_DIM + c] = acc[r] + bia;
  }
}

// ---------------------------------------------------------------------------
// Small GEMM for Wfused = Wo @ Wv (bf16 out): m97-style 128x128 tile, BK=64.
// ---------------------------------------------------------------------------
__global__ __launch_bounds__(256) void gemm_bt_kernel(
    const ushort* __restrict__ A, const ushort* __restrict__ Bm,
    ushort* __restrict__ Cb, int K, int N)
{
  __shared__ ushort As[128][64];   // 16 KB
  __shared__ ushort Bs[128][64];   // 16 KB
  const int tid  = threadIdx.x;
  const int wave = tid >> 6;
  const int lane = tid & 63;
  const int wm = wave >> 1, wn = wave & 1;
  const int n0 = blockIdx.x * 128, m0 = blockIdx.y * 128;
  const int l15 = lane & 15, lhi = lane >> 4;

  floatx4 acc[4][4] = {};

  const int srow = tid >> 3;
  const int sk8  = (tid & 7) * 8;
  const ushort* Ab = A  + (size_t)(m0 + srow) * K + sk8;
  const ushort* Bb = Bm + (size_t)(n0 + srow) * K + sk8;

  for (int k0 = 0; k0 < K; k0 += 64) {
#pragma unroll
    for (int q = 0; q < 4; ++q)
      __builtin_amdgcn_global_load_lds((gptr_t)(Ab + k0 + (size_t)q * 32 * K),
          (lptr_t)((char*)&As[0][0] + (q * 256 + wave * 64) * 16), 16, 0, 0);
#pragma unroll
    for (int q = 0; q < 4; ++q)
      __builtin_amdgcn_global_load_lds((gptr_t)(Bb + k0 + (size_t)q * 32 * K),
          (lptr_t)((char*)&Bs[0][0] + (q * 256 + wave * 64) * 16), 16, 0, 0);
    __syncthreads();

#pragma unroll
    for (int kk = 0; kk < 2; ++kk) {
      short8 af[4], bfrg[4];
#pragma unroll
      for (int i = 0; i < 4; ++i) {
        af[i]   = *(const short8*)(&As[wm * 64 + i * 16 + l15][kk * 32 + lhi * 8]);
        bfrg[i] = *(const short8*)(&Bs[wn * 64 + i * 16 + l15][kk * 32 + lhi * 8]);
      }
#pragma unroll
      for (int mi = 0; mi < 4; ++mi)
#pragma unroll
        for (int ni = 0; ni < 4; ++ni)
          acc[mi][ni] = __builtin_amdgcn_mfma_f32_16x16x32_bf16(
              af[mi], bfrg[ni], acc[mi][ni], 0, 0, 0);
    }
    __syncthreads();
  }

#pragma unroll
  for (int mi = 0; mi < 4; ++mi)
#pragma unroll
    for (int ni = 0; ni < 4; ++ni) {
      const int gn = n0 + wn * 64 + ni * 16 + l15;
#pragma unroll
      for (int j = 0; j < 4; ++j) {
        const int gm = m0 + wm * 64 + mi * 16 + lhi * 4 + j;
        Cb[(size_t)gm * N + gn] = f2bf(acc[mi][ni][j]);
      }
    }
}

// ---------------------------------------------------------------------------
// Depthwise temporal conv -> s_bf16 (standalone; r15-proven).
// s[t] = sum_i w[i] x[t-32+i] (x[neg]=0), t in [0,4096].
// Ascending recurrence with batched 32-row register window + exact resync:
//   s[t] = (s[t-1] - w0*x[t-33]) / r + w31*x[t-1]
// CTCH=256: reads 1.125 rows/output. Grid (16, 8, 4) = 512 blocks.
// ---------------------------------------------------------------------------
#define CTCH 256
__global__ __launch_bounds__(256) void conv_kernel(
    const float* __restrict__ x, const float* __restrict__ dw,
    ushort* __restrict__ S)
{
  const int b   = blockIdx.y;
  const int col = blockIdx.z * 256 + threadIdx.x;   // 0..1023
  const int t0  = blockIdx.x * CTCH;

  float w[32];
#pragma unroll
  for (int i = 0; i < 32; ++i) w[i] = dw[i];
  const float rinv = w[0] / w[1];                    // 1/r
  const float w31  = w[31];
  const float c0   = -w[0] * rinv;                   // -(w0/r)

  const float* xb = x + (size_t)b * T_DIM * D_DIM + col;
  ushort*      Sb = S + (size_t)b * (T_DIM + 1) * D_DIM + col;

  float prev[32], cur[32];
  float s;
  if (blockIdx.x == 0) {
#pragma unroll
    for (int i = 0; i < 32; ++i) prev[i] = 0.f;
    s = 0.f;
    Sb[0] = f2bf(0.f);                               // row t=0
  } else {
#pragma unroll
    for (int i = 0; i < 32; ++i) prev[i] = xb[(size_t)(t0 - 32 + i) * D_DIM];
    s = 0.f;
#pragma unroll
    for (int i = 0; i < 32; ++i) s = __builtin_fmaf(w[i], prev[i], s);
  }

#pragma unroll 1
  for (int g = 0; g < 8; g += 2) {
#pragma unroll
    for (int i = 0; i < 32; ++i) cur[i] = xb[(size_t)(t0 + g * 32 + i) * D_DIM];
#pragma unroll
    for (int j = 0; j < 32; ++j) {
      s = __builtin_fmaf(s, rinv, __builtin_fmaf(prev[j], c0, w31 * cur[j]));
      Sb[(size_t)(t0 + g * 32 + 1 + j) * D_DIM] = f2bf(s);
    }
    s = 0.f;                                         // exact resync from cur
#pragma unroll
    for (int i = 0; i < 32; ++i) s = __builtin_fmaf(w[i], cur[i], s);
#pragma unroll
    for (int i = 0; i < 32; ++i) prev[i] = xb[(size_t)(t0 + (g + 1) * 32 + i) * D_DIM];
#pragma unroll
    for (int j = 0; j < 32; ++j) {
      s = __builtin_fmaf(s, rinv, __builtin_fmaf(cur[j], c0, w31 * prev[j]));
      Sb[(size_t)(t0 + (g + 1) * 32 + 1 + j) * D_DIM] = f2bf(s);
    }
    s = 0.f;
#pragma unroll
    for (int i = 0; i < 32; ++i) s = __builtin_fmaf(w[i], prev[i], s);
  }
}

// ---------------------------------------------------------------------------
// Merged weight prep: blocks [0,1024): Wo->bf16; [1024,2048): Wv->WvT bf16;
// [2048,2304): cvec[j] = sum(dw)*dot(Wo[j,:],bv) + bo[j].
// ---------------------------------------------------------------------------
__global__ __launch_bounds__(256) void prep_kernel(
    const float* __restrict__ Wo, const float* __restrict__ Wv,
    const float* __restrict__ bv, const float* __restrict__ bo,
    const float* __restrict__ dw,
    ushort* __restrict__ WoB, ushort* __restrict__ WvT,
    float* __restrict__ cvec)
{
  __shared__ float tile[32][33];
  const int bid = blockIdx.x;
  const int tid = threadIdx.x;

  if (bid < 1024) {            // Wo fp32 -> bf16 straight copy (float4)
    const int i = bid * 256 + tid;
    const float4 v = ((const float4*)Wo)[i];
    ushort4 o = make_ushort4(f2bf(v.x), f2bf(v.y), f2bf(v.z), f2bf(v.w));
    *(ushort4*)(WoB + (size_t)i * 4) = o;
  } else if (bid < 2048) {     // Wv transpose -> WvT bf16 (32x32 LDS tile)
    const int b2 = bid - 1024;
    const int c0 = (b2 & 31) * 32, r0 = (b2 >> 5) * 32;
    const int tx = tid & 31, ty = tid >> 5;    // 32 x 8
#pragma unroll
    for (int j = 0; j < 4; ++j)
      tile[ty + j * 8][tx] = Wv[(size_t)(r0 + ty + j * 8) * D_DIM + c0 + tx];
    __syncthreads();
#pragma unroll
    for (int j = 0; j < 4; ++j)
      WvT[(size_t)(c0 + ty + j * 8) * D_DIM + r0 + tx] = f2bf(tile[tx][ty + j * 8]);
  } else {                     // bias vector, one wave per j
    const int j    = (bid - 2048) * 4 + (tid >> 6);
    const int lane = tid & 63;
    float sumw = 0.f;
#pragma unroll
    for (int i = 0; i < 32; ++i) sumw += dw[i];
    float s = 0.f;
    for (int k = lane; k < D_DIM; k += 64) s += Wo[(size_t)j * D_DIM + k] * bv[k];
#pragma unroll
    for (int off = 32; off; off >>= 1) s += __shfl_xor(s, off, 64);
    if (lane == 0) cvec[j] = sumw * s + bo[j];
  }
}

// ---------------------------------------------------------------------------
extern "C" void kernel_launch(void* const* d_in, const int* in_sizes, int n_in,
                              void* d_out, int out_size, void* d_ws, size_t ws_size,
                              hipStream_t stream) {
  const float* x  = (const float*)d_in[0];
  const float* Wv = (const float*)d_in[1];
  const float* bv = (const float*)d_in[2];
  const float* Wo = (const float*)d_in[3];
  const float* bo = (const float*)d_in[4];
  const float* dw = (const float*)d_in[5];
  float* out = (float*)d_out;

  // Workspace layout (~73.4 MB total).
  char* ws = (char*)d_ws;
  ushort* S      = (ushort*)ws;                                  // M_REAL*1024 bf16
  ushort* WoB    = (ushort*)(ws + (size_t)M_REAL * D_DIM * 2);   // 1024^2 bf16
  ushort* WvT    = WoB + (size_t)D_DIM * D_DIM;                  // 1024^2 bf16
  ushort* Wfused = WvT + (size_t)D_DIM * D_DIM;                  // 1024^2 bf16
  float*  cvec   = (float*)(Wfused + (size_t)D_DIM * D_DIM);     // 1024 fp32

  // 1) Merged weight prep.
  prep_kernel<<<dim3(2304), dim3(256), 0, stream>>>(
      Wo, Wv, bv, bo, dw, WoB, WvT, cvec);

  // 2) Wfused = Wo @ Wv  (standalone, pristine codegen).
  gemm_bt_kernel<<<dim3(8, 8), dim3(256), 0, stream>>>(
      WoB, WvT, Wfused, D_DIM, D_DIM);

  // 3) Temporal conv -> s bf16 (standalone, pristine codegen).
  conv_kernel<<<dim3(T_DIM / CTCH, B_DIM, 4), dim3(256), 0, stream>>>(x, dw, S);

  // 4) out = s @ Wfused^T + cvec  (256^2, 16-wave BK32, 3-buf 96KB,
  //    ONE barrier/K-tile, counted vmcnt(2), XCD-swizzled).
  gemm_w16_kernel<<<dim3(NWG), dim3(1024), 0, stream>>>(S, Wfused, out, cvec);

  // 5) 8-row tail GEMV (tiny).
  tail_gemv_kernel<<<dim3(256), dim3(256), 0, stream>>>(S, Wfused, cvec, out);
}